// Round 3
// baseline (50.691 us; speedup 1.0000x reference)
//
#include <hip/hip_runtime.h>
#include <math.h>

#define NB 128
#define NC 8
#define NV 16384
#define NK 64
#define NR 128

// flat output offsets (elements, f32)
#define OFF_MASKS  0
#define OFF_VP     2097152
#define OFF_THETAS 8388608
#define OFF_ALPHAS 8388736
#define OFF_ROT    8388864
#define OFF_SCALES 8389376
#define OFF_DEPTHS 8389504
#define OFF_C2D    8389632
#define OFF_TRANS  8389888
#define OFF_CLP    8390272

#define PI_F     3.14159265358979323846f
#define TWOPI_F  6.28318530717958647692f

// d_ws layout (W_i = int view, W_f = float view):
//   W_i[0..8]      class_start (prefix counts)
//   W_i[16+r]      batch id of record r           (r = 0..127, class-sorted)
//   W_f[160+r*8]   params: scale,qw,qy,tx,ty,tz,feff,pad
//   W_f[1184+r*192] coeffs (K=64 x 3), contiguous per record
// total = (1184 + 128*192)*4 = 103,040 bytes

__device__ __forceinline__ float rflf(float x) {
  return __int_as_float(__builtin_amdgcn_readfirstlane(__float_as_int(x)));
}

// ---- kernel 1: zero masks (grid-wide); block 0: scalars + sorted work queue -
__global__ __launch_bounds__(256) void prep_kernel(
    const float* __restrict__ roi, const float* __restrict__ focals,
    const float* __restrict__ td,  const float* __restrict__ t2,
    const float* __restrict__ ls,  const float* __restrict__ ld,
    const float* __restrict__ cp,  const float* __restrict__ fc,
    float* __restrict__ out, int* __restrict__ Wi, float* __restrict__ Wf) {
  int tid = threadIdx.x;
  int i = blockIdx.x * 256 + tid;
  float4 z; z.x = 0.0f; z.y = 0.0f; z.z = 0.0f; z.w = 0.0f;
  ((float4*)(out + OFF_MASKS))[i] = z;   // 2048*256 = 524288 float4 = full mask
  if (blockIdx.x != 0) return;

  __shared__ int cls_sh[NB];
  int b = tid;
  float scale = 0, qw = 0, qy = 0, tx_ = 0, ty_ = 0, tz_ = 0, feff = 0;
  int cls = 0;
  if (b < NB) {
    float r0 = roi[b * 4 + 0], r1 = roi[b * 4 + 1];
    float r2 = roi[b * 4 + 2], r3 = roi[b * 4 + 3];
    float dx = r2 - r0, dy = r3 - r1;
    float mx = 0.5f * (r2 + r0), my = 0.5f * (r3 + r1);
    float theta = atan2f(td[b * 2 + 1], td[b * 2 + 0]);
    qw = cosf(0.5f * theta);
    qy = sinf(0.5f * theta);
    float area  = dx * dy;
    scale = expf(ls[b]);
    float depth = sqrtf(expf(ld[b]) / area);
    float cx = mx + t2[b * 2 + 0] * dx;
    float cy = my + t2[b * 2 + 1] * dy;
    float tux = cy, tuy = -cx;
    float n = sqrtf(tux * tux + tuy * tuy + 1.0f);
    tx_ = depth * (tux / n);
    ty_ = depth * (tuy / n);
    tz_ = depth * (-1.0f / n);
    float alpha = -(theta - atanf(tx_ / tz_));
    float a  = alpha + PI_F;
    float rr = fmodf(a, TWOPI_F);
    if (rr < 0.0f) rr += TWOPI_F;
    float alpha_out = rr - PI_F;
    float pmax = cp[b * NC];
    for (int c = 1; c < NC; ++c) {
      float pv = cp[b * NC + c];
      if (pv > pmax) { pmax = pv; cls = c; }
    }
    feff = 2.0f * focals[b] / (float)NR;

    out[OFF_THETAS + b]      = theta;
    out[OFF_ALPHAS + b]      = alpha_out;
    out[OFF_ROT + 4 * b + 0] = qw;
    out[OFF_ROT + 4 * b + 1] = 0.0f;
    out[OFF_ROT + 4 * b + 2] = qy;
    out[OFF_ROT + 4 * b + 3] = 0.0f;
    out[OFF_SCALES + b]      = scale;
    out[OFF_DEPTHS + b]      = depth;
    out[OFF_C2D + 2 * b + 0] = cx;
    out[OFF_C2D + 2 * b + 1] = cy;
    out[OFF_TRANS + 3 * b + 0] = tx_;
    out[OFF_TRANS + 3 * b + 1] = ty_;
    out[OFF_TRANS + 3 * b + 2] = tz_;
    out[OFF_CLP + b]         = logf(pmax);
    cls_sh[b] = cls;
  }
  __syncthreads();
  if (b < NB) {
    // stable counting-sort rank by (class, batch)
    int rank = 0;
    for (int j = 0; j < NB; ++j) {
      int cj = cls_sh[j];
      rank += (cj < cls) || (cj == cls && j < b);
    }
    Wi[16 + rank] = b;
    float* par = Wf + 160 + rank * 8;
    par[0] = scale; par[1] = qw; par[2] = qy; par[3] = tx_;
    par[4] = ty_;   par[5] = tz_; par[6] = feff; par[7] = 0.0f;
    const float4* src = (const float4*)(fc + ((size_t)(b * NC + cls)) * 192);
    float4* dst = (float4*)(Wf + 1184 + (size_t)rank * 192);
#pragma unroll 8
    for (int t = 0; t < 48; ++t) dst[t] = src[t];
  }
  if (b <= NC) {
    int cnt = 0;
    for (int j = 0; j < NB; ++j) cnt += (cls_sh[j] < b);
    Wi[b] = cnt;
  }
}

// ---- kernel 2: class-major FFD + transform + project + scatter --------------
// grid (512, 2): class = bx&7, vtile = bx>>3; y splits the slot range.
// basis row pinned in VGPRs; coeff/params via uniform scalar loads.

#define KSTEP(i) {                                                             \
    float4 c0 = cc[3 * (i) + 0];                                               \
    float4 c1 = cc[3 * (i) + 1];                                               \
    float4 c2 = cc[3 * (i) + 2];                                               \
    float4 bv = bs[(i)];                                                       \
    dxv = fmaf(bv.x, c0.x, dxv); dyv = fmaf(bv.x, c0.y, dyv); dzv = fmaf(bv.x, c0.z, dzv); \
    dxv = fmaf(bv.y, c0.w, dxv); dyv = fmaf(bv.y, c1.x, dyv); dzv = fmaf(bv.y, c1.y, dzv); \
    dxv = fmaf(bv.z, c1.z, dxv); dyv = fmaf(bv.z, c1.w, dyv); dzv = fmaf(bv.z, c2.x, dzv); \
    dxv = fmaf(bv.w, c2.y, dxv); dyv = fmaf(bv.w, c2.z, dyv); dzv = fmaf(bv.w, c2.w, dzv); }

__global__ __launch_bounds__(256, 3) void verts_kernel(
    const float* __restrict__ basev,    // (C, V, 3)
    const float* __restrict__ basis,    // (C, V, K)
    const int*   __restrict__ Wi,
    const float* __restrict__ Wf,
    float* __restrict__ out) {
  int bx   = blockIdx.x;
  int myc  = bx & 7;
  int tile = bx >> 3;
  int v    = tile * 256 + threadIdx.x;

  const float4* brow = (const float4*)(basis + ((size_t)myc * NV + v) * NK);
  float4 bs[16];
#pragma unroll
  for (int i = 0; i < 16; ++i) bs[i] = brow[i];
  const float* bp = basev + ((size_t)myc * NV + v) * 3;
  float bpx = bp[0], bpy = bp[1], bpz = bp[2];

  int s0 = Wi[myc];
  int s1 = Wi[myc + 1];

  for (int slot = s0 + (int)blockIdx.y; slot < s1; slot += 2) {
    int b = __builtin_amdgcn_readfirstlane(Wi[16 + slot]);
    const float4* cc = (const float4*)(Wf + 1184 + (size_t)slot * 192);
    float dxv = 0.0f, dyv = 0.0f, dzv = 0.0f;
    KSTEP(0)  KSTEP(1)  KSTEP(2)  KSTEP(3)
    KSTEP(4)  KSTEP(5)  KSTEP(6)  KSTEP(7)
    KSTEP(8)  KSTEP(9)  KSTEP(10) KSTEP(11)
    KSTEP(12) KSTEP(13) KSTEP(14) KSTEP(15)

    const float* pp = Wf + 160 + slot * 8;
    float scale = rflf(pp[0]);
    float qw    = rflf(pp[1]);
    float qy    = rflf(pp[2]);
    float tx    = rflf(pp[3]);
    float ty    = rflf(pp[4]);
    float tz    = rflf(pp[5]);
    float feff  = rflf(pp[6]);

    float vx = (bpx + dxv) * scale;
    float vy = (bpy + dyv) * scale;
    float vz = (bpz + dzv) * scale;
    float t2x = 2.0f * qy * vz;
    float t2z = -2.0f * qy * vx;
    float rx = vx + qw * t2x + qy * t2z;
    float ry = vy;
    float rz = vz + qw * t2z - qy * t2x;
    float wx = rx + tx, wy = ry + ty, wz = rz + tz;

    float zv = wz;
    float zsafe = (zv > -1e-4f) ? -1e-4f : zv;
    float inv = feff / (-zsafe);
    float u  = wx * inv;
    float vv = wy * inv;
    float px = (u * 0.5f + 0.5f) * (float)NR;
    float py = (vv * 0.5f + 0.5f) * (float)NR;

    float* o = out + OFF_VP + (size_t)(b * NV + v) * 3;
    o[0] = px; o[1] = py; o[2] = -zv;

    int xi = (int)fminf(fmaxf(px, 0.0f), 127.0f);
    int yi = (int)fminf(fmaxf(py, 0.0f), 127.0f);
    out[OFF_MASKS + (b << 14) + yi * NR + xi] = 1.0f;
  }
}

extern "C" void kernel_launch(void* const* d_in, const int* in_sizes, int n_in,
                              void* d_out, int out_size, void* d_ws, size_t ws_size,
                              hipStream_t stream) {
  const float* roi    = (const float*)d_in[0];
  const float* focals = (const float*)d_in[1];
  const float* td     = (const float*)d_in[2];
  const float* t2     = (const float*)d_in[3];
  const float* ls     = (const float*)d_in[4];
  const float* ld     = (const float*)d_in[5];
  const float* cp     = (const float*)d_in[6];
  const float* fc     = (const float*)d_in[7];
  const float* bv     = (const float*)d_in[8];
  const float* fb     = (const float*)d_in[9];
  float* out = (float*)d_out;
  int*   Wi  = (int*)d_ws;
  float* Wf  = (float*)d_ws;

  prep_kernel<<<dim3(2048), dim3(256), 0, stream>>>(
      roi, focals, td, t2, ls, ld, cp, fc, out, Wi, Wf);
  verts_kernel<<<dim3(512, 2), dim3(256), 0, stream>>>(
      bv, fb, Wi, Wf, out);
}